// Round 9
// baseline (1432.786 us; speedup 1.0000x reference)
//
#include <hip/hip_runtime.h>
#include <cmath>

#define LRELU(x) fmaxf((x), 0.01f * (x))

typedef __attribute__((ext_vector_type(8))) short short8;
typedef __attribute__((ext_vector_type(4))) float f32x4;
typedef __attribute__((ext_vector_type(2))) unsigned uint2v;

constexpr int RS = 1032;   // LDS hi-plane row stride (shorts); RS/2=516 floats

__device__ __forceinline__ unsigned short f2bf(float f) {
    return __builtin_bit_cast(unsigned short, (__bf16)f);   // hw RNE cvt on gfx950
}
__device__ __forceinline__ float bf2f(unsigned short h) {
    return __uint_as_float((unsigned)h << 16);
}
__device__ __forceinline__ unsigned pk2(unsigned short a, unsigned short b) {
    return (unsigned)a | ((unsigned)b << 16);
}

// ---------------------------------------------------------------------------
// sgrid[t][c] = sin(r_t * 2^((c/2)/2))  (256 x 32, fp64 math)
// ---------------------------------------------------------------------------
__global__ void sgrid_kernel(float* __restrict__ sg) {
    int idx = blockIdx.x * blockDim.x + threadIdx.x;
    if (idx >= 256 * 32) return;
    int t = idx >> 5, c = idx & 31;
    double r = (double)(t - 128) * 3.14159265358979323846 / 256.0;
    double scale = exp2(0.5 * (double)(c >> 1));
    sg[idx] = (float)sin(r * scale);
}

// ---------------------------------------------------------------------------
// Conv: grid (oc, ic-chunk of 64), 256 thr = 64 px x 4 subs, LDS weights,
// LDS reduce, one atomicAdd per px per block.
// ---------------------------------------------------------------------------
__global__ __launch_bounds__(256) void conv_part(
    const float* __restrict__ x, const float* __restrict__ w,
    float* __restrict__ y, int Cin_g, int Cout_g, int Hin, int pad) {
    __shared__ float wsh[64 * 9];
    __shared__ float red[256];
    int oc = blockIdx.x, ch = blockIdx.y;
    int Hout = pad ? Hin : Hin - 2;
    int t = threadIdx.x;
    int ic0 = ch * 64;
    int nic = min(64, Cin_g - ic0);
    const float* wb = w + ((size_t)oc * Cin_g + ic0) * 9;
    for (int i = t; i < nic * 9; i += 256) wsh[i] = wb[i];
    __syncthreads();
    int p = t & 63, sub = t >> 6;
    int oy = p / Hout, ox = p % Hout;
    int g = oc / Cout_g;
    const float* xb = x + ((size_t)g * Cin_g + ic0) * Hin * Hin;
    bool valid = p < Hout * Hout;
    float acc = 0.f;
    if (valid) {
        for (int ic = sub; ic < nic; ic += 4) {
            const float* xc = xb + (size_t)ic * Hin * Hin;
            const float* wc = wsh + ic * 9;
            #pragma unroll
            for (int ky = 0; ky < 3; ++ky) {
                int iy = oy + ky - pad;
                if (iy < 0 || iy >= Hin) continue;
                #pragma unroll
                for (int kx = 0; kx < 3; ++kx) {
                    int ix = ox + kx - pad;
                    if (ix < 0 || ix >= Hin) continue;
                    acc = fmaf(xc[iy * Hin + ix], wc[ky * 3 + kx], acc);
                }
            }
        }
    }
    red[t] = acc;
    __syncthreads();
    if (t < 64 && valid)
        atomicAdd(&y[(size_t)oc * Hout * Hout + p],
                  red[t] + red[t + 64] + red[t + 128] + red[t + 192]);
}

__global__ void conv_finalize(float* __restrict__ y, const float* __restrict__ bias,
                              int HH, int n) {
    int i = blockIdx.x * 256 + threadIdx.x;
    if (i >= n) return;
    float v = y[i] + bias[i / HH];
    y[i] = LRELU(v);
}

// ---------------------------------------------------------------------------
// c1[o] = b1[o] + feat . w1[o][32:]
// ---------------------------------------------------------------------------
__global__ void feat_c1_kernel(const float* __restrict__ feat, const float* __restrict__ w1,
                               const float* __restrict__ b1, float* __restrict__ c1) {
    int o = (blockIdx.x * blockDim.x + threadIdx.x) >> 6;
    int lane = threadIdx.x & 63;
    if (o >= 1024) return;
    const float* wr = w1 + (size_t)o * 2080 + 32;
    float sum = 0.f;
    for (int k = lane; k < 2048; k += 64) sum += feat[k] * wr[k];
    #pragma unroll
    for (int off = 32; off; off >>= 1) sum += __shfl_xor(sum, off);
    if (lane == 0) c1[o] = sum + b1[o];
}

// ---------------------------------------------------------------------------
// wn_scale: s[r] = g[r]/||v[r,:]||
// ---------------------------------------------------------------------------
__global__ __launch_bounds__(256) void wn_scale(const float* __restrict__ v, const float* __restrict__ g,
                                                float* __restrict__ s, int K) {
    __shared__ float red[256];
    int r = blockIdx.x, t = threadIdx.x;
    const float* vr = v + (size_t)r * K;
    float sum = 0.f;
    for (int k = t; k < K; k += 256) { float x = vr[k]; sum = fmaf(x, x, sum); }
    red[t] = sum;
    __syncthreads();
    for (int o = 128; o; o >>= 1) {
        if (t < o) red[t] += red[t + o];
        __syncthreads();
    }
    if (t == 0) s[r] = g[r] / sqrtf(red[0]);
}

// ---------------------------------------------------------------------------
// repack: fp32 weights -> bf16 MFMA fragment streams (lane-contiguous 1KB/wave)
// ---------------------------------------------------------------------------
__global__ void repack_kernel(const float* __restrict__ v, unsigned short* __restrict__ dst,
                              int T, int N, int K, int NT, int ldk, int koff) {
    int W = N / (NT * 16);
    int KC = K / 32;
    size_t total = (size_t)T * W * NT * KC * 64;
    size_t fi = (size_t)blockIdx.x * 256 + threadIdx.x;
    if (fi >= total) return;
    int l = fi & 63;
    size_t r = fi >> 6;
    int kc = r % KC; r /= KC;
    int nt = r % NT; r /= NT;
    int w  = r % W;  r /= W;
    int t  = (int)r;
    int n = w * NT * 16 + nt * 16 + (l & 15);
    int k = kc * 32 + (l >> 4) * 8;
    const float* src = v + ((size_t)t * N + n) * ldk + koff + k;
    unsigned short* d = dst + fi * 8;
    #pragma unroll
    for (int e = 0; e < 8; ++e) d[e] = f2bf(src[e]);
}

// w2 repack with stack-2-aligned output-column ownership:
// col = (nt<2) ? w*32+nt*16+l15 : 256 + w*32 + (nt-2)*16 + l15
__global__ void repack_w2k(const float* __restrict__ w2, unsigned short* __restrict__ dst) {
    int fi = blockIdx.x * 256 + threadIdx.x;   // 8*4*32*64 = 65536
    if (fi >= 65536) return;
    int l = fi & 63;
    int r = fi >> 6;
    int kc = r & 31; r >>= 5;
    int nt = r & 3;  r >>= 2;
    int w = r;
    int l15 = l & 15;
    int col = (nt < 2) ? (w * 32 + nt * 16 + l15) : (256 + w * 32 + (nt - 2) * 16 + l15);
    int k = kc * 32 + (l >> 4) * 8;
    const float* src = w2 + (size_t)col * 1056 + 32 + k;
    unsigned short* d = dst + (size_t)fi * 8;
    #pragma unroll
    for (int e = 0; e < 8; ++e) d[e] = f2bf(src[e]);
}

// ---------------------------------------------------------------------------
// Px/Py, Qx/Qy separable grid tables
// ---------------------------------------------------------------------------
__global__ void pxy_kernel(const float* __restrict__ sg, const float* __restrict__ w1,
                           const float* __restrict__ c1, float* __restrict__ Px,
                           float* __restrict__ Py) {
    int idx = blockIdx.x * 256 + threadIdx.x;  // 256*1024
    int t = idx >> 10, o = idx & 1023;
    const float* wr = w1 + (size_t)o * 2080;
    const float* sr = sg + t * 32;
    float px = 0.f, py = 0.f;
    #pragma unroll
    for (int k = 0; k < 16; ++k) {
        px = fmaf(sr[2 * k], wr[2 * k], px);
        py = fmaf(sr[2 * k + 1], wr[2 * k + 1], py);
    }
    Px[idx] = px + c1[o];
    Py[idx] = py;
}

__global__ void qxy_kernel(const float* __restrict__ sg, const float* __restrict__ w2,
                           float* __restrict__ Qx, float* __restrict__ Qy) {
    int idx = blockIdx.x * 256 + threadIdx.x;  // 256*512
    int t = idx >> 9, o = idx & 511;
    const float* wr = w2 + (size_t)o * 1056;
    const float* sr = sg + t * 32;
    float qx = 0.f, qy = 0.f;
    #pragma unroll
    for (int k = 0; k < 16; ++k) {
        qx = fmaf(sr[2 * k], wr[2 * k], qx);
        qy = fmaf(sr[2 * k + 1], wr[2 * k + 1], qy);
    }
    Qx[idx] = qx;
    Qy[idx] = qy;
}

// ---------------------------------------------------------------------------
// Fused MLP. fp32 residual master lives in the OWNING WAVE'S VGPRs; LDS holds
// only the bf16 hi image (A-operand). __launch_bounds__(512,1): 132KB LDS
// already limits to 1 block/CU (2 waves/SIMD), so allow the full 512-VGPR
// budget -> no scratch spills (round-8's 183MB WRITE_SIZE pathology).
// ---------------------------------------------------------------------------
__device__ __forceinline__ void step1(unsigned short* sm, int w, int l, int l15, int lq,
                                      int srcb, int dstb,
                                      const unsigned short* __restrict__ Bp,
                                      const float* __restrict__ sc,
                                      const float* __restrict__ bi,
                                      f32x4* master) {
    f32x4 acc[4][4] = {};
    const unsigned short* wb = Bp + (size_t)w * (4 * 16 * 512) + (size_t)l * 8;
    const unsigned short* abase = sm + (size_t)l15 * RS + srcb + lq * 8;
    short8 b0[4], b1[4];
    #pragma unroll
    for (int nt = 0; nt < 4; ++nt) b0[nt] = *(const short8*)(wb + (size_t)(nt * 16 + 0) * 512);
    #pragma unroll
    for (int nt = 0; nt < 4; ++nt) b1[nt] = *(const short8*)(wb + (size_t)(nt * 16 + 1) * 512);
    #pragma unroll
    for (int kc = 0; kc < 16; ++kc) {
        short8 bn[4];
        if (kc < 14) {
            #pragma unroll
            for (int nt = 0; nt < 4; ++nt)
                bn[nt] = *(const short8*)(wb + (size_t)(nt * 16 + kc + 2) * 512);
        }
        short8 af[4];
        #pragma unroll
        for (int mt = 0; mt < 4; ++mt)
            af[mt] = *(const short8*)(abase + (size_t)(mt * 16) * RS + kc * 32);
        #pragma unroll
        for (int mt = 0; mt < 4; ++mt)
            #pragma unroll
            for (int nt = 0; nt < 4; ++nt)
                acc[mt][nt] = __builtin_amdgcn_mfma_f32_16x16x32_bf16(b0[nt], af[mt], acc[mt][nt], 0, 0, 0);
        #pragma unroll
        for (int nt = 0; nt < 4; ++nt) { b0[nt] = b1[nt]; b1[nt] = bn[nt]; }
    }
    #pragma unroll
    for (int nt = 0; nt < 4; ++nt) {
        int nb = w * 64 + nt * 16 + lq * 4;
        float4 s4 = *(const float4*)(sc + nb);
        float4 bb = *(const float4*)(bi + nb);
        #pragma unroll
        for (int mt = 0; mt < 4; ++mt) {
            int row = mt * 16 + l15;
            f32x4 m = master[mt * 4 + nt];
            float v0 = LRELU(acc[mt][nt][0] * s4.x + bb.x) + m[0];
            float v1 = LRELU(acc[mt][nt][1] * s4.y + bb.y) + m[1];
            float v2 = LRELU(acc[mt][nt][2] * s4.z + bb.z) + m[2];
            float v3 = LRELU(acc[mt][nt][3] * s4.w + bb.w) + m[3];
            m[0] = v0; m[1] = v1; m[2] = v2; m[3] = v3;
            master[mt * 4 + nt] = m;
            uint2v hv; hv[0] = pk2(f2bf(v0), f2bf(v1)); hv[1] = pk2(f2bf(v2), f2bf(v3));
            *(uint2v*)(sm + (size_t)row * RS + dstb + nb) = hv;
        }
    }
}

__device__ __forceinline__ void step2(unsigned short* sm, int w, int l, int l15, int lq,
                                      int srcb, int dstb,
                                      const unsigned short* __restrict__ Bp,
                                      const float* __restrict__ sc,
                                      const float* __restrict__ bi,
                                      f32x4* master) {
    f32x4 acc[4][2] = {};
    const unsigned short* wb = Bp + (size_t)w * (2 * 8 * 512) + (size_t)l * 8;
    const unsigned short* abase = sm + (size_t)l15 * RS + srcb + lq * 8;
    short8 b0[2], b1[2];
    #pragma unroll
    for (int nt = 0; nt < 2; ++nt) b0[nt] = *(const short8*)(wb + (size_t)(nt * 8 + 0) * 512);
    #pragma unroll
    for (int nt = 0; nt < 2; ++nt) b1[nt] = *(const short8*)(wb + (size_t)(nt * 8 + 1) * 512);
    #pragma unroll
    for (int kc = 0; kc < 8; ++kc) {
        short8 bn[2];
        if (kc < 6) {
            #pragma unroll
            for (int nt = 0; nt < 2; ++nt)
                bn[nt] = *(const short8*)(wb + (size_t)(nt * 8 + kc + 2) * 512);
        }
        short8 af[4];
        #pragma unroll
        for (int mt = 0; mt < 4; ++mt)
            af[mt] = *(const short8*)(abase + (size_t)(mt * 16) * RS + kc * 32);
        #pragma unroll
        for (int mt = 0; mt < 4; ++mt)
            #pragma unroll
            for (int nt = 0; nt < 2; ++nt)
                acc[mt][nt] = __builtin_amdgcn_mfma_f32_16x16x32_bf16(b0[nt], af[mt], acc[mt][nt], 0, 0, 0);
        #pragma unroll
        for (int nt = 0; nt < 2; ++nt) { b0[nt] = b1[nt]; b1[nt] = bn[nt]; }
    }
    #pragma unroll
    for (int nt = 0; nt < 2; ++nt) {
        int nb = w * 32 + nt * 16 + lq * 4;
        float4 s4 = *(const float4*)(sc + nb);
        float4 bb = *(const float4*)(bi + nb);
        #pragma unroll
        for (int mt = 0; mt < 4; ++mt) {
            int row = mt * 16 + l15;
            f32x4 m = master[mt * 2 + nt];
            float v0 = LRELU(acc[mt][nt][0] * s4.x + bb.x) + m[0];
            float v1 = LRELU(acc[mt][nt][1] * s4.y + bb.y) + m[1];
            float v2 = LRELU(acc[mt][nt][2] * s4.z + bb.z) + m[2];
            float v3 = LRELU(acc[mt][nt][3] * s4.w + bb.w) + m[3];
            m[0] = v0; m[1] = v1; m[2] = v2; m[3] = v3;
            master[mt * 2 + nt] = m;
            uint2v hv; hv[0] = pk2(f2bf(v0), f2bf(v1)); hv[1] = pk2(f2bf(v2), f2bf(v3));
            *(uint2v*)(sm + (size_t)row * RS + dstb + nb) = hv;
        }
    }
}

__global__ __launch_bounds__(512, 1) void fused_mlp(
    const float* __restrict__ Px, const float* __restrict__ Py,
    const float* __restrict__ Qx, const float* __restrict__ Qy,
    const unsigned short* __restrict__ m1f, const float* __restrict__ s1f, const float* __restrict__ bf1,
    const unsigned short* __restrict__ m1g, const float* __restrict__ s1g, const float* __restrict__ bg1,
    const unsigned short* __restrict__ w2m, const float* __restrict__ b2,
    const unsigned short* __restrict__ m2f, const float* __restrict__ s2f, const float* __restrict__ bf2_,
    const unsigned short* __restrict__ m2g, const float* __restrict__ s2g, const float* __restrict__ bg2_,
    const float* __restrict__ w3, const float* __restrict__ b3,
    float* __restrict__ out) {
    extern __shared__ unsigned short sm[];     // [64][RS] bf16 hi plane
    int tid = threadIdx.x;
    int w = tid >> 6, l = tid & 63;
    int l15 = l & 15, lq = l >> 4;
    int n0 = blockIdx.x * 64;
    int i = n0 >> 8, jb = n0 & 255;

    f32x4 mh[32];   // fp32 master: [half(2)][mt(4)][nt(4)]  (stack-2: [half][mt][nt2] in mh[0..7]/mh[16..23])

    // ---- P1: mid init; hi -> LDS, fp32 -> master regs ----
    #pragma unroll
    for (int h = 0; h < 2; ++h) {
        #pragma unroll
        for (int nt = 0; nt < 4; ++nt) {
            int nb = h * 512 + w * 64 + nt * 16 + lq * 4;
            float4 px4 = *(const float4*)(Px + (size_t)i * 1024 + nb);
            #pragma unroll
            for (int mt = 0; mt < 4; ++mt) {
                int row = mt * 16 + l15;
                float4 py4 = *(const float4*)(Py + (size_t)(jb + row) * 1024 + nb);
                f32x4 m;
                m[0] = LRELU(px4.x + py4.x);
                m[1] = LRELU(px4.y + py4.y);
                m[2] = LRELU(px4.z + py4.z);
                m[3] = LRELU(px4.w + py4.w);
                mh[h * 16 + mt * 4 + nt] = m;
                uint2v hv; hv[0] = pk2(f2bf(m[0]), f2bf(m[1])); hv[1] = pk2(f2bf(m[2]), f2bf(m[3]));
                *(uint2v*)(sm + (size_t)row * RS + nb) = hv;
            }
        }
    }
    __syncthreads();

    // ---- P2: stack 1 ----
    for (int t = 0; t < 8; ++t) {
        step1(sm, w, l, l15, lq, 512, 0, m1f + (size_t)t * 512 * 512, s1f + t * 512, bf1 + t * 512, mh);
        __syncthreads();
        step1(sm, w, l, l15, lq, 0, 512, m1g + (size_t)t * 512 * 512, s1g + t * 512, bg1 + t * 512, mh + 16);
        __syncthreads();
    }

    // ---- P3: h2 = lrelu(Qx+Qy + mid @ w2m^T + b2); re-init master ----
    {
        f32x4 acc[4][4] = {};
        const unsigned short* wb = w2m + (size_t)w * (4 * 32 * 512) + (size_t)l * 8;
        const unsigned short* abase = sm + (size_t)l15 * RS + lq * 8;
        short8 b0[4], b1[4];
        #pragma unroll
        for (int nt = 0; nt < 4; ++nt) b0[nt] = *(const short8*)(wb + (size_t)(nt * 32 + 0) * 512);
        #pragma unroll
        for (int nt = 0; nt < 4; ++nt) b1[nt] = *(const short8*)(wb + (size_t)(nt * 32 + 1) * 512);
        #pragma unroll
        for (int kc = 0; kc < 32; ++kc) {
            short8 bn[4];
            if (kc < 30) {
                #pragma unroll
                for (int nt = 0; nt < 4; ++nt)
                    bn[nt] = *(const short8*)(wb + (size_t)(nt * 32 + kc + 2) * 512);
            }
            short8 af[4];
            #pragma unroll
            for (int mt = 0; mt < 4; ++mt)
                af[mt] = *(const short8*)(abase + (size_t)(mt * 16) * RS + kc * 32);
            #pragma unroll
            for (int mt = 0; mt < 4; ++mt)
                #pragma unroll
                for (int nt = 0; nt < 4; ++nt)
                    acc[mt][nt] = __builtin_amdgcn_mfma_f32_16x16x32_bf16(b0[nt], af[mt], acc[mt][nt], 0, 0, 0);
            #pragma unroll
            for (int nt = 0; nt < 4; ++nt) { b0[nt] = b1[nt]; b1[nt] = bn[nt]; }
        }
        __syncthreads();   // all A reads of mid done before overwrite
        #pragma unroll
        for (int nt = 0; nt < 4; ++nt) {
            // stack-2-aligned ownership (matches repack_w2k)
            int colb = ((nt < 2) ? (w * 32 + nt * 16) : (256 + w * 32 + (nt - 2) * 16)) + lq * 4;
            float4 qx4 = *(const float4*)(Qx + (size_t)i * 512 + colb);
            float4 b24 = *(const float4*)(b2 + colb);
            #pragma unroll
            for (int mt = 0; mt < 4; ++mt) {
                int row = mt * 16 + l15;
                float4 qy4 = *(const float4*)(Qy + (size_t)(jb + row) * 512 + colb);
                f32x4 m;
                m[0] = LRELU(acc[mt][nt][0] + qx4.x + qy4.x + b24.x);
                m[1] = LRELU(acc[mt][nt][1] + qx4.y + qy4.y + b24.y);
                m[2] = LRELU(acc[mt][nt][2] + qx4.z + qy4.z + b24.z);
                m[3] = LRELU(acc[mt][nt][3] + qx4.w + qy4.w + b24.w);
                mh[(nt >> 1) * 16 + mt * 2 + (nt & 1)] = m;
                uint2v hv; hv[0] = pk2(f2bf(m[0]), f2bf(m[1])); hv[1] = pk2(f2bf(m[2]), f2bf(m[3]));
                *(uint2v*)(sm + (size_t)row * RS + colb) = hv;
            }
        }
    }
    __syncthreads();

    // ---- P4: stack 2 ----
    for (int t = 0; t < 8; ++t) {
        step2(sm, w, l, l15, lq, 256, 0, m2f + (size_t)t * 256 * 256, s2f + t * 256, bf2_ + t * 256, mh);
        __syncthreads();
        step2(sm, w, l, l15, lq, 0, 256, m2g + (size_t)t * 256 * 256, s2g + t * 256, bg2_ + t * 256, mh + 16);
        __syncthreads();
    }

    // ---- P5: dump fp32 master to LDS (float view, stride RS/2), then rgb ----
    __syncthreads();
    {
        float* smf = (float*)sm;
        #pragma unroll
        for (int hh = 0; hh < 2; ++hh)
            #pragma unroll
            for (int nt = 0; nt < 2; ++nt) {
                int colb = hh * 256 + w * 32 + nt * 16 + lq * 4;
                #pragma unroll
                for (int mt = 0; mt < 4; ++mt) {
                    int row = mt * 16 + l15;
                    f32x4 m = mh[hh * 16 + mt * 2 + nt];
                    *(f32x4*)(smf + (size_t)row * (RS / 2) + colb) = m;
                }
            }
    }
    __syncthreads();
    {
        const float* smf = (const float*)sm;
        #pragma unroll
        for (int rr = 0; rr < 8; ++rr) {
            int row = w * 8 + rr;
            float s0 = 0.f, s1 = 0.f, s2 = 0.f;
            #pragma unroll
            for (int it = 0; it < 8; ++it) {
                int k = it * 64 + l;
                float hv = smf[(size_t)row * (RS / 2) + k];
                s0 = fmaf(hv, w3[k], s0);
                s1 = fmaf(hv, w3[512 + k], s1);
                s2 = fmaf(hv, w3[1024 + k], s2);
            }
            #pragma unroll
            for (int off = 32; off; off >>= 1) {
                s0 += __shfl_xor(s0, off);
                s1 += __shfl_xor(s1, off);
                s2 += __shfl_xor(s2, off);
            }
            if (l == 0) {
                float v[3] = {s0 + b3[0], s1 + b3[1], s2 + b3[2]};
                #pragma unroll
                for (int c = 0; c < 3; ++c) {
                    float sg = 1.0f / (1.0f + expf(-v[c]));
                    out[(size_t)c * 65536 + n0 + row] = 1.1f * sg - 0.05f;
                }
            }
        }
    }
}

extern "C" void kernel_launch(void* const* d_in, const int* in_sizes, int n_in,
                              void* d_out, int out_size, void* d_ws, size_t ws_size,
                              hipStream_t stream) {
    const float* feature = (const float*)d_in[0];
    const float* cw1 = (const float*)d_in[1];  const float* cb1 = (const float*)d_in[2];
    const float* cw2 = (const float*)d_in[3];  const float* cb2 = (const float*)d_in[4];
    const float* cw3 = (const float*)d_in[5];  const float* cb3 = (const float*)d_in[6];
    const float* cw4 = (const float*)d_in[7];  const float* cb4 = (const float*)d_in[8];
    const float* cw5 = (const float*)d_in[9];  const float* cb5 = (const float*)d_in[10];
    const float* w1  = (const float*)d_in[11]; const float* b1  = (const float*)d_in[12];
    const float* m1_vf = (const float*)d_in[13]; const float* m1_gf = (const float*)d_in[14];
    const float* m1_bf = (const float*)d_in[15];
    const float* m1_vg = (const float*)d_in[16]; const float* m1_gg = (const float*)d_in[17];
    const float* m1_bg = (const float*)d_in[18];
    const float* w2  = (const float*)d_in[19]; const float* b2  = (const float*)d_in[20];
    const float* m2_vf = (const float*)d_in[21]; const float* m2_gf = (const float*)d_in[22];
    const float* m2_bf = (const float*)d_in[23];
    const float* m2_vg = (const float*)d_in[24]; const float* m2_gg = (const float*)d_in[25];
    const float* m2_bg = (const float*)d_in[26];
    const float* w3  = (const float*)d_in[27]; const float* b3  = (const float*)d_in[28];
    float* out = (float*)d_out;

    float* ws = (float*)d_ws;
    size_t off = 0;
    float* sgrid   = ws + off; off += 256 * 32;
    float* cbA     = ws + off; off += 768 * 64;
    float* cbB     = ws + off; off += 768 * 64;
    float* featbuf = ws + off; off += 2048;
    float* c1      = ws + off; off += 1024;
    float* s1f     = ws + off; off += 8 * 512;
    float* s1g     = ws + off; off += 8 * 512;
    float* s2f     = ws + off; off += 8 * 256;
    float* s2g     = ws + off; off += 8 * 256;
    float* Px      = ws + off; off += 256 * 1024;
    float* Py      = ws + off; off += 256 * 1024;
    float* Qx      = ws + off; off += 256 * 512;
    float* Qy      = ws + off; off += 256 * 512;
    unsigned short* m1f_p = (unsigned short*)(ws + off); off += (size_t)8 * 512 * 512 / 2;
    unsigned short* m1g_p = (unsigned short*)(ws + off); off += (size_t)8 * 512 * 512 / 2;
    unsigned short* m2f_p = (unsigned short*)(ws + off); off += (size_t)8 * 256 * 256 / 2;
    unsigned short* m2g_p = (unsigned short*)(ws + off); off += (size_t)8 * 256 * 256 / 2;
    unsigned short* w2m_p = (unsigned short*)(ws + off); off += (size_t)512 * 1024 / 2;

    // ---- constants ----
    sgrid_kernel<<<32, 256, 0, stream>>>(sgrid);
    wn_scale<<<8 * 512, 256, 0, stream>>>(m1_vf, m1_gf, s1f, 512);
    wn_scale<<<8 * 512, 256, 0, stream>>>(m1_vg, m1_gg, s1g, 512);
    wn_scale<<<8 * 256, 256, 0, stream>>>(m2_vf, m2_gf, s2f, 256);
    wn_scale<<<8 * 256, 256, 0, stream>>>(m2_vg, m2_gg, s2g, 256);
    repack_kernel<<<1024, 256, 0, stream>>>(m1_vf, m1f_p, 8, 512, 512, 4, 512, 0);
    repack_kernel<<<1024, 256, 0, stream>>>(m1_vg, m1g_p, 8, 512, 512, 4, 512, 0);
    repack_kernel<<<256, 256, 0, stream>>>(m2_vf, m2f_p, 8, 256, 256, 2, 256, 0);
    repack_kernel<<<256, 256, 0, stream>>>(m2_vg, m2g_p, 8, 256, 256, 2, 256, 0);
    repack_w2k<<<256, 256, 0, stream>>>(w2, w2m_p);

    // ---- conv trunk: zero -> partials (atomic) -> bias+lrelu ----
    hipMemsetAsync(cbA, 0, 768 * 64 * sizeof(float), stream);
    conv_part<<<dim3(768, 7), 256, 0, stream>>>(feature, cw1, cbA, 448, 192, 8, 1);
    conv_finalize<<<(768 * 64) / 256, 256, 0, stream>>>(cbA, cb1, 64, 768 * 64);
    hipMemsetAsync(cbB, 0, 768 * 64 * sizeof(float), stream);
    conv_part<<<dim3(768, 4), 256, 0, stream>>>(cbA, cw2, cbB, 256, 256, 8, 1);
    conv_finalize<<<(768 * 64) / 256, 256, 0, stream>>>(cbB, cb2, 64, 768 * 64);
    hipMemsetAsync(cbA, 0, 768 * 64 * sizeof(float), stream);
    conv_part<<<dim3(768, 6), 256, 0, stream>>>(cbB, cw3, cbA, 384, 384, 8, 1);
    conv_finalize<<<(768 * 64) / 256, 256, 0, stream>>>(cbA, cb3, 64, 768 * 64);
    hipMemsetAsync(cbB, 0, 768 * 36 * sizeof(float), stream);
    conv_part<<<dim3(768, 4), 256, 0, stream>>>(cbA, cw4, cbB, 256, 256, 8, 0);     // ->6x6
    conv_finalize<<<(768 * 36 + 255) / 256, 256, 0, stream>>>(cbB, cb4, 36, 768 * 36);
    hipMemsetAsync(featbuf, 0, 2048 * sizeof(float), stream);
    conv_part<<<dim3(128, 12), 256, 0, stream>>>(cbB, cw5, featbuf, 768, 128, 6, 0); // ->4x4
    conv_finalize<<<(2048 + 255) / 256, 256, 0, stream>>>(featbuf, cb5, 16, 2048);

    // ---- c1, Px/Py, Qx/Qy ----
    feat_c1_kernel<<<1024 / 4, 256, 0, stream>>>(featbuf, w1, b1, c1);
    pxy_kernel<<<(256 * 1024) / 256, 256, 0, stream>>>(sgrid, w1, c1, Px, Py);
    qxy_kernel<<<(256 * 512) / 256, 256, 0, stream>>>(sgrid, w2, Qx, Qy);

    // ---- fused per-position MLP: 1024 blocks x 64 rows ----
    size_t lds_bytes = (size_t)64 * RS * sizeof(unsigned short);   // 132096
    hipFuncSetAttribute(reinterpret_cast<const void*>(fused_mlp),
                        hipFuncAttributeMaxDynamicSharedMemorySize, (int)lds_bytes);
    fused_mlp<<<1024, 512, lds_bytes, stream>>>(
        Px, Py, Qx, Qy,
        m1f_p, s1f, m1_bf, m1g_p, s1g, m1_bg,
        w2m_p, b2,
        m2f_p, s2f, m2_bf, m2g_p, s2g, m2_bg,
        w3, b3, out);
}

// Round 10
// 1282.193 us; speedup vs baseline: 1.1174x; 1.1174x over previous
//
#include <hip/hip_runtime.h>
#include <cmath>

#define LRELU(x) fmaxf((x), 0.01f * (x))

typedef __attribute__((ext_vector_type(8))) short short8;
typedef __attribute__((ext_vector_type(4))) float f32x4;
typedef __attribute__((ext_vector_type(2))) unsigned uint2v;

constexpr int RS = 1032;   // LDS hi-plane row stride (shorts)

__device__ __forceinline__ unsigned short f2bf(float f) {
    return __builtin_bit_cast(unsigned short, (__bf16)f);   // hw RNE cvt
}
__device__ __forceinline__ unsigned pk2(unsigned short a, unsigned short b) {
    return (unsigned)a | ((unsigned)b << 16);
}
__device__ __forceinline__ uint2v cvt4(f32x4 v) {
    uint2v r;
    r[0] = pk2(f2bf(v[0]), f2bf(v[1]));
    r[1] = pk2(f2bf(v[2]), f2bf(v[3]));
    return r;
}
__device__ __forceinline__ f32x4 unpk4(uint2v p) {   // 4 x 1-op bf16->f32
    f32x4 r;
    r[0] = __uint_as_float(p[0] << 16);
    r[1] = __uint_as_float(p[0] & 0xffff0000u);
    r[2] = __uint_as_float(p[1] << 16);
    r[3] = __uint_as_float(p[1] & 0xffff0000u);
    return r;
}
__device__ __forceinline__ f32x4 lrelu4(f32x4 v) {
    return __builtin_elementwise_max(v, 0.01f * v);
}

// ---------------------------------------------------------------------------
// sgrid[t][c] = sin(r_t * 2^((c/2)/2))  (256 x 32, fp64 math)
// ---------------------------------------------------------------------------
__global__ void sgrid_kernel(float* __restrict__ sg) {
    int idx = blockIdx.x * blockDim.x + threadIdx.x;
    if (idx >= 256 * 32) return;
    int t = idx >> 5, c = idx & 31;
    double r = (double)(t - 128) * 3.14159265358979323846 / 256.0;
    double scale = exp2(0.5 * (double)(c >> 1));
    sg[idx] = (float)sin(r * scale);
}

// ---------------------------------------------------------------------------
// Conv: grid (oc, ic-chunk of 64), 256 thr, LDS weights, atomic partials.
// ---------------------------------------------------------------------------
__global__ __launch_bounds__(256) void conv_part(
    const float* __restrict__ x, const float* __restrict__ w,
    float* __restrict__ y, int Cin_g, int Cout_g, int Hin, int pad) {
    __shared__ float wsh[64 * 9];
    __shared__ float red[256];
    int oc = blockIdx.x, ch = blockIdx.y;
    int Hout = pad ? Hin : Hin - 2;
    int t = threadIdx.x;
    int ic0 = ch * 64;
    int nic = min(64, Cin_g - ic0);
    const float* wb = w + ((size_t)oc * Cin_g + ic0) * 9;
    for (int i = t; i < nic * 9; i += 256) wsh[i] = wb[i];
    __syncthreads();
    int p = t & 63, sub = t >> 6;
    int oy = p / Hout, ox = p % Hout;
    int g = oc / Cout_g;
    const float* xb = x + ((size_t)g * Cin_g + ic0) * Hin * Hin;
    bool valid = p < Hout * Hout;
    float acc = 0.f;
    if (valid) {
        for (int ic = sub; ic < nic; ic += 4) {
            const float* xc = xb + (size_t)ic * Hin * Hin;
            const float* wc = wsh + ic * 9;
            #pragma unroll
            for (int ky = 0; ky < 3; ++ky) {
                int iy = oy + ky - pad;
                if (iy < 0 || iy >= Hin) continue;
                #pragma unroll
                for (int kx = 0; kx < 3; ++kx) {
                    int ix = ox + kx - pad;
                    if (ix < 0 || ix >= Hin) continue;
                    acc = fmaf(xc[iy * Hin + ix], wc[ky * 3 + kx], acc);
                }
            }
        }
    }
    red[t] = acc;
    __syncthreads();
    if (t < 64 && valid)
        atomicAdd(&y[(size_t)oc * Hout * Hout + p],
                  red[t] + red[t + 64] + red[t + 128] + red[t + 192]);
}

__global__ void conv_finalize(float* __restrict__ y, const float* __restrict__ bias,
                              int HH, int n) {
    int i = blockIdx.x * 256 + threadIdx.x;
    if (i >= n) return;
    float v = y[i] + bias[i / HH];
    y[i] = LRELU(v);
}

// ---------------------------------------------------------------------------
// c1[o] = b1[o] + feat . w1[o][32:]
// ---------------------------------------------------------------------------
__global__ void feat_c1_kernel(const float* __restrict__ feat, const float* __restrict__ w1,
                               const float* __restrict__ b1, float* __restrict__ c1) {
    int o = (blockIdx.x * blockDim.x + threadIdx.x) >> 6;
    int lane = threadIdx.x & 63;
    if (o >= 1024) return;
    const float* wr = w1 + (size_t)o * 2080 + 32;
    float sum = 0.f;
    for (int k = lane; k < 2048; k += 64) sum += feat[k] * wr[k];
    #pragma unroll
    for (int off = 32; off; off >>= 1) sum += __shfl_xor(sum, off);
    if (lane == 0) c1[o] = sum + b1[o];
}

// ---------------------------------------------------------------------------
// All four weight-norm scales in ONE dispatch (block per row).
// ---------------------------------------------------------------------------
__global__ __launch_bounds__(256) void wn_all(
    const float* __restrict__ v1f, const float* __restrict__ g1f, float* __restrict__ s1f,
    const float* __restrict__ v1g, const float* __restrict__ g1g, float* __restrict__ s1g,
    const float* __restrict__ v2f, const float* __restrict__ g2f, float* __restrict__ s2f,
    const float* __restrict__ v2g, const float* __restrict__ g2g, float* __restrict__ s2g) {
    __shared__ float red[256];
    int b = blockIdx.x, t = threadIdx.x;
    const float* v; const float* g; float* s; int K, r;
    if (b < 4096)       { v = v1f; g = g1f; s = s1f; K = 512; r = b; }
    else if (b < 8192)  { v = v1g; g = g1g; s = s1g; K = 512; r = b - 4096; }
    else if (b < 10240) { v = v2f; g = g2f; s = s2f; K = 256; r = b - 8192; }
    else                { v = v2g; g = g2g; s = s2g; K = 256; r = b - 10240; }
    const float* vr = v + (size_t)r * K;
    float sum = 0.f;
    for (int k = t; k < K; k += 256) { float x = vr[k]; sum = fmaf(x, x, sum); }
    red[t] = sum;
    __syncthreads();
    for (int o = 128; o; o >>= 1) {
        if (t < o) red[t] += red[t + o];
        __syncthreads();
    }
    if (t == 0) s[r] = g[r] / sqrtf(red[0]);
}

// ---------------------------------------------------------------------------
// All weight repacks (fp32 -> bf16 fragment streams) in ONE dispatch.
// ---------------------------------------------------------------------------
__device__ __forceinline__ void repack_one(const float* __restrict__ v, unsigned short* __restrict__ dst,
                                           int N, int NT, int KC, int ldk, int koff, size_t fi) {
    int W = N / (NT * 16);
    int l = (int)(fi & 63);
    size_t r = fi >> 6;
    int kc = r % KC; r /= KC;
    int nt = r % NT; r /= NT;
    int w  = r % W;  r /= W;
    int t  = (int)r;
    int n = w * NT * 16 + nt * 16 + (l & 15);
    int k = kc * 32 + (l >> 4) * 8;
    const float* src = v + ((size_t)t * N + n) * ldk + koff + k;
    unsigned short* d = dst + fi * 8;
    #pragma unroll
    for (int e = 0; e < 8; ++e) d[e] = f2bf(src[e]);
}

__global__ void repack_all(const float* __restrict__ m1vf, const float* __restrict__ m1vg,
                           const float* __restrict__ m2vf, const float* __restrict__ m2vg,
                           const float* __restrict__ w2,
                           unsigned short* __restrict__ p1f, unsigned short* __restrict__ p1g,
                           unsigned short* __restrict__ p2f, unsigned short* __restrict__ p2g,
                           unsigned short* __restrict__ pw2) {
    size_t fi = (size_t)blockIdx.x * 256 + threadIdx.x;   // 2816 blocks
    const size_t n1 = 262144, n2 = 65536;
    if (fi < n1)                repack_one(m1vf, p1f, 512, 4, 16, 512, 0, fi);
    else if (fi < 2 * n1)       repack_one(m1vg, p1g, 512, 4, 16, 512, 0, fi - n1);
    else if (fi < 2 * n1 + n2)  repack_one(m2vf, p2f, 256, 2, 8, 256, 0, fi - 2 * n1);
    else if (fi < 2 * n1 + 2 * n2) repack_one(m2vg, p2g, 256, 2, 8, 256, 0, fi - 2 * n1 - n2);
    else                        repack_one(w2, pw2, 512, 4, 32, 1056, 32, fi - 2 * n1 - 2 * n2);
}

// ---------------------------------------------------------------------------
// Px/Py (w1) + Qx/Qy (w2) separable grid tables in ONE dispatch.
// ---------------------------------------------------------------------------
__global__ void pq_kernel(const float* __restrict__ sg, const float* __restrict__ w1,
                          const float* __restrict__ c1, const float* __restrict__ w2,
                          float* __restrict__ Px, float* __restrict__ Py,
                          float* __restrict__ Qx, float* __restrict__ Qy) {
    int idx = blockIdx.x * 256 + threadIdx.x;
    if (idx < 256 * 1024) {
        int t = idx >> 10, o = idx & 1023;
        const float* wr = w1 + (size_t)o * 2080;
        const float* sr = sg + t * 32;
        float px = 0.f, py = 0.f;
        #pragma unroll
        for (int k = 0; k < 16; ++k) {
            px = fmaf(sr[2 * k], wr[2 * k], px);
            py = fmaf(sr[2 * k + 1], wr[2 * k + 1], py);
        }
        Px[idx] = px + c1[o];
        Py[idx] = py;
    } else {
        int j = idx - 256 * 1024;      // 256*512
        int t = j >> 9, o = j & 511;
        const float* wr = w2 + (size_t)o * 1056;
        const float* sr = sg + t * 32;
        float qx = 0.f, qy = 0.f;
        #pragma unroll
        for (int k = 0; k < 16; ++k) {
            qx = fmaf(sr[2 * k], wr[2 * k], qx);
            qy = fmaf(sr[2 * k + 1], wr[2 * k + 1], qy);
        }
        Qx[j] = qx;
        Qy[j] = qy;
    }
}

// ---------------------------------------------------------------------------
// Fused MLP (round-7 structure, vectorized epilogue). Master = bf16 hi in LDS
// + bf16 lo residual: stack-1 lo in VGPRs (uint2v pairs), stack-2 lo in LDS
// cols 512..1023. Swapped-operand MFMA -> b64 epilogue.
// ---------------------------------------------------------------------------
__device__ __forceinline__ void step1(unsigned short* sm, int w, int l, int l15, int lq,
                                      int srcb, int dstb,
                                      const unsigned short* __restrict__ Bp,
                                      const float* __restrict__ sc,
                                      const float* __restrict__ bi,
                                      uint2v* lo_half) {
    f32x4 acc[4][4] = {};
    const unsigned short* wb = Bp + (size_t)w * (4 * 16 * 512) + (size_t)l * 8;
    const unsigned short* abase = sm + (size_t)l15 * RS + srcb + lq * 8;
    short8 b0[4], b1[4];
    #pragma unroll
    for (int nt = 0; nt < 4; ++nt) b0[nt] = *(const short8*)(wb + (size_t)(nt * 16 + 0) * 512);
    #pragma unroll
    for (int nt = 0; nt < 4; ++nt) b1[nt] = *(const short8*)(wb + (size_t)(nt * 16 + 1) * 512);
    #pragma unroll
    for (int kc = 0; kc < 16; ++kc) {
        short8 bn[4];
        if (kc < 14) {
            #pragma unroll
            for (int nt = 0; nt < 4; ++nt)
                bn[nt] = *(const short8*)(wb + (size_t)(nt * 16 + kc + 2) * 512);
        }
        short8 af[4];
        #pragma unroll
        for (int mt = 0; mt < 4; ++mt)
            af[mt] = *(const short8*)(abase + (size_t)(mt * 16) * RS + kc * 32);
        #pragma unroll
        for (int mt = 0; mt < 4; ++mt)
            #pragma unroll
            for (int nt = 0; nt < 4; ++nt)
                acc[mt][nt] = __builtin_amdgcn_mfma_f32_16x16x32_bf16(b0[nt], af[mt], acc[mt][nt], 0, 0, 0);
        #pragma unroll
        for (int nt = 0; nt < 4; ++nt) { b0[nt] = b1[nt]; b1[nt] = bn[nt]; }
    }
    #pragma unroll
    for (int nt = 0; nt < 4; ++nt) {
        int nb = w * 64 + nt * 16 + lq * 4;
        f32x4 s4 = *(const f32x4*)(sc + nb);
        f32x4 bb = *(const f32x4*)(bi + nb);
        #pragma unroll
        for (int mt = 0; mt < 4; ++mt) {
            int row = mt * 16 + l15;
            size_t hidx = (size_t)row * RS + dstb + nb;
            uint2v hold = *(uint2v*)(sm + hidx);
            f32x4 v = lrelu4(acc[mt][nt] * s4 + bb);
            v += unpk4(hold) + unpk4(lo_half[mt * 4 + nt]);
            uint2v hnew = cvt4(v);
            *(uint2v*)(sm + hidx) = hnew;
            lo_half[mt * 4 + nt] = cvt4(v - unpk4(hnew));
        }
    }
}

__device__ __forceinline__ void step2(unsigned short* sm, int w, int l, int l15, int lq,
                                      int srcb, int dstb,
                                      const unsigned short* __restrict__ Bp,
                                      const float* __restrict__ sc,
                                      const float* __restrict__ bi) {
    f32x4 acc[4][2] = {};
    const unsigned short* wb = Bp + (size_t)w * (2 * 8 * 512) + (size_t)l * 8;
    const unsigned short* abase = sm + (size_t)l15 * RS + srcb + lq * 8;
    short8 b0[2], b1[2];
    #pragma unroll
    for (int nt = 0; nt < 2; ++nt) b0[nt] = *(const short8*)(wb + (size_t)(nt * 8 + 0) * 512);
    #pragma unroll
    for (int nt = 0; nt < 2; ++nt) b1[nt] = *(const short8*)(wb + (size_t)(nt * 8 + 1) * 512);
    #pragma unroll
    for (int kc = 0; kc < 8; ++kc) {
        short8 bn[2];
        if (kc < 6) {
            #pragma unroll
            for (int nt = 0; nt < 2; ++nt)
                bn[nt] = *(const short8*)(wb + (size_t)(nt * 8 + kc + 2) * 512);
        }
        short8 af[4];
        #pragma unroll
        for (int mt = 0; mt < 4; ++mt)
            af[mt] = *(const short8*)(abase + (size_t)(mt * 16) * RS + kc * 32);
        #pragma unroll
        for (int mt = 0; mt < 4; ++mt)
            #pragma unroll
            for (int nt = 0; nt < 2; ++nt)
                acc[mt][nt] = __builtin_amdgcn_mfma_f32_16x16x32_bf16(b0[nt], af[mt], acc[mt][nt], 0, 0, 0);
        #pragma unroll
        for (int nt = 0; nt < 2; ++nt) { b0[nt] = b1[nt]; b1[nt] = bn[nt]; }
    }
    #pragma unroll
    for (int nt = 0; nt < 2; ++nt) {
        int nb = w * 32 + nt * 16 + lq * 4;
        f32x4 s4 = *(const f32x4*)(sc + nb);
        f32x4 bb = *(const f32x4*)(bi + nb);
        #pragma unroll
        for (int mt = 0; mt < 4; ++mt) {
            int row = mt * 16 + l15;
            size_t hidx = (size_t)row * RS + dstb + nb;
            uint2v hold = *(uint2v*)(sm + hidx);
            uint2v lold = *(uint2v*)(sm + hidx + 512);
            f32x4 v = lrelu4(acc[mt][nt] * s4 + bb);
            v += unpk4(hold) + unpk4(lold);
            uint2v hnew = cvt4(v);
            *(uint2v*)(sm + hidx) = hnew;
            *(uint2v*)(sm + hidx + 512) = cvt4(v - unpk4(hnew));
        }
    }
}

__global__ __launch_bounds__(512, 2) void fused_mlp(
    const float* __restrict__ Px, const float* __restrict__ Py,
    const float* __restrict__ Qx, const float* __restrict__ Qy,
    const unsigned short* __restrict__ m1f, const float* __restrict__ s1f, const float* __restrict__ bf1,
    const unsigned short* __restrict__ m1g, const float* __restrict__ s1g, const float* __restrict__ bg1,
    const unsigned short* __restrict__ w2m, const float* __restrict__ b2,
    const unsigned short* __restrict__ m2f, const float* __restrict__ s2f, const float* __restrict__ bf2_,
    const unsigned short* __restrict__ m2g, const float* __restrict__ s2g, const float* __restrict__ bg2_,
    const float* __restrict__ w3, const float* __restrict__ b3,
    float* __restrict__ out) {
    extern __shared__ unsigned short sm[];     // [64][RS] bf16 hi plane
    int tid = threadIdx.x;
    int w = tid >> 6, l = tid & 63;
    int l15 = l & 15, lq = l >> 4;
    int n0 = blockIdx.x * 64;
    int i = n0 >> 8, jb = n0 & 255;

    uint2v lo_pk[32];   // stack-1 lo plane: [half(2)][mt(4)][nt(4)]

    // ---- P1: mid init; hi -> LDS (b64), lo -> VGPR ----
    #pragma unroll
    for (int h = 0; h < 2; ++h) {
        #pragma unroll
        for (int nt = 0; nt < 4; ++nt) {
            int nb = h * 512 + w * 64 + nt * 16 + lq * 4;
            f32x4 px4 = *(const f32x4*)(Px + (size_t)i * 1024 + nb);
            #pragma unroll
            for (int mt = 0; mt < 4; ++mt) {
                int row = mt * 16 + l15;
                f32x4 py4 = *(const f32x4*)(Py + (size_t)(jb + row) * 1024 + nb);
                f32x4 v = lrelu4(px4 + py4);
                uint2v hv = cvt4(v);
                *(uint2v*)(sm + (size_t)row * RS + nb) = hv;
                lo_pk[h * 16 + mt * 4 + nt] = cvt4(v - unpk4(hv));
            }
        }
    }
    __syncthreads();

    // ---- P2: stack 1 ----
    for (int t = 0; t < 8; ++t) {
        step1(sm, w, l, l15, lq, 512, 0, m1f + (size_t)t * 512 * 512, s1f + t * 512, bf1 + t * 512, lo_pk);
        __syncthreads();
        step1(sm, w, l, l15, lq, 0, 512, m1g + (size_t)t * 512 * 512, s1g + t * 512, bg1 + t * 512, lo_pk + 16);
        __syncthreads();
    }

    // ---- P3: h2 = lrelu(Qx+Qy + mid @ w2m^T + b2); overwrite master ----
    {
        f32x4 acc[4][4] = {};
        const unsigned short* wb = w2m + (size_t)w * (4 * 32 * 512) + (size_t)l * 8;
        const unsigned short* abase = sm + (size_t)l15 * RS + lq * 8;
        short8 b0[4], b1[4];
        #pragma unroll
        for (int nt = 0; nt < 4; ++nt) b0[nt] = *(const short8*)(wb + (size_t)(nt * 32 + 0) * 512);
        #pragma unroll
        for (int nt = 0; nt < 4; ++nt) b1[nt] = *(const short8*)(wb + (size_t)(nt * 32 + 1) * 512);
        #pragma unroll
        for (int kc = 0; kc < 32; ++kc) {
            short8 bn[4];
            if (kc < 30) {
                #pragma unroll
                for (int nt = 0; nt < 4; ++nt)
                    bn[nt] = *(const short8*)(wb + (size_t)(nt * 32 + kc + 2) * 512);
            }
            short8 af[4];
            #pragma unroll
            for (int mt = 0; mt < 4; ++mt)
                af[mt] = *(const short8*)(abase + (size_t)(mt * 16) * RS + kc * 32);
            #pragma unroll
            for (int mt = 0; mt < 4; ++mt)
                #pragma unroll
                for (int nt = 0; nt < 4; ++nt)
                    acc[mt][nt] = __builtin_amdgcn_mfma_f32_16x16x32_bf16(b0[nt], af[mt], acc[mt][nt], 0, 0, 0);
            #pragma unroll
            for (int nt = 0; nt < 4; ++nt) { b0[nt] = b1[nt]; b1[nt] = bn[nt]; }
        }
        __syncthreads();   // all A reads of mid done before overwrite
        #pragma unroll
        for (int nt = 0; nt < 4; ++nt) {
            int nb = w * 64 + nt * 16 + lq * 4;      // 0..511
            f32x4 qx4 = *(const f32x4*)(Qx + (size_t)i * 512 + nb);
            f32x4 b24 = *(const f32x4*)(b2 + nb);
            #pragma unroll
            for (int mt = 0; mt < 4; ++mt) {
                int row = mt * 16 + l15;
                f32x4 qy4 = *(const f32x4*)(Qy + (size_t)(jb + row) * 512 + nb);
                f32x4 v = lrelu4(acc[mt][nt] + qx4 + qy4 + b24);
                uint2v hv = cvt4(v);
                size_t hidx = (size_t)row * RS + nb;
                *(uint2v*)(sm + hidx) = hv;
                *(uint2v*)(sm + hidx + 512) = cvt4(v - unpk4(hv));
            }
        }
    }
    __syncthreads();

    // ---- P4: stack 2 ----
    for (int t = 0; t < 8; ++t) {
        step2(sm, w, l, l15, lq, 256, 0, m2f + (size_t)t * 256 * 256, s2f + t * 256, bf2_ + t * 256);
        __syncthreads();
        step2(sm, w, l, l15, lq, 0, 256, m2g + (size_t)t * 256 * 256, s2g + t * 256, bg2_ + t * 256);
        __syncthreads();
    }

    // ---- P5: rgb ----
    #pragma unroll
    for (int rr = 0; rr < 8; ++rr) {
        int row = w * 8 + rr;
        float s0 = 0.f, s1 = 0.f, s2 = 0.f;
        #pragma unroll
        for (int it = 0; it < 8; ++it) {
            int k = it * 64 + l;
            size_t hidx = (size_t)row * RS + k;
            float hv = __uint_as_float((unsigned)sm[hidx] << 16) +
                       __uint_as_float((unsigned)sm[hidx + 512] << 16);
            s0 = fmaf(hv, w3[k], s0);
            s1 = fmaf(hv, w3[512 + k], s1);
            s2 = fmaf(hv, w3[1024 + k], s2);
        }
        #pragma unroll
        for (int off = 32; off; off >>= 1) {
            s0 += __shfl_xor(s0, off);
            s1 += __shfl_xor(s1, off);
            s2 += __shfl_xor(s2, off);
        }
        if (l == 0) {
            float v[3] = {s0 + b3[0], s1 + b3[1], s2 + b3[2]};
            #pragma unroll
            for (int c = 0; c < 3; ++c) {
                float sg = 1.0f / (1.0f + expf(-v[c]));
                out[(size_t)c * 65536 + n0 + row] = 1.1f * sg - 0.05f;
            }
        }
    }
}

extern "C" void kernel_launch(void* const* d_in, const int* in_sizes, int n_in,
                              void* d_out, int out_size, void* d_ws, size_t ws_size,
                              hipStream_t stream) {
    const float* feature = (const float*)d_in[0];
    const float* cw1 = (const float*)d_in[1];  const float* cb1 = (const float*)d_in[2];
    const float* cw2 = (const float*)d_in[3];  const float* cb2 = (const float*)d_in[4];
    const float* cw3 = (const float*)d_in[5];  const float* cb3 = (const float*)d_in[6];
    const float* cw4 = (const float*)d_in[7];  const float* cb4 = (const float*)d_in[8];
    const float* cw5 = (const float*)d_in[9];  const float* cb5 = (const float*)d_in[10];
    const float* w1  = (const float*)d_in[11]; const float* b1  = (const float*)d_in[12];
    const float* m1_vf = (const float*)d_in[13]; const float* m1_gf = (const float*)d_in[14];
    const float* m1_bf = (const float*)d_in[15];
    const float* m1_vg = (const float*)d_in[16]; const float* m1_gg = (const float*)d_in[17];
    const float* m1_bg = (const float*)d_in[18];
    const float* w2  = (const float*)d_in[19]; const float* b2  = (const float*)d_in[20];
    const float* m2_vf = (const float*)d_in[21]; const float* m2_gf = (const float*)d_in[22];
    const float* m2_bf = (const float*)d_in[23];
    const float* m2_vg = (const float*)d_in[24]; const float* m2_gg = (const float*)d_in[25];
    const float* m2_bg = (const float*)d_in[26];
    const float* w3  = (const float*)d_in[27]; const float* b3  = (const float*)d_in[28];
    float* out = (float*)d_out;

    float* ws = (float*)d_ws;
    size_t off = 0;
    float* sgrid   = ws + off; off += 256 * 32;
    // conv buffers (contiguous -> single memset)
    float* cbA     = ws + off; off += 768 * 64;
    float* cbB     = ws + off; off += 768 * 64;
    float* cbC     = ws + off; off += 768 * 64;
    float* cbD     = ws + off; off += 768 * 36;
    float* featbuf = ws + off; off += 2048;
    size_t convN   = 768 * 64 * 3 + 768 * 36 + 2048;
    float* c1      = ws + off; off += 1024;
    float* s1f     = ws + off; off += 8 * 512;
    float* s1g     = ws + off; off += 8 * 512;
    float* s2f     = ws + off; off += 8 * 256;
    float* s2g     = ws + off; off += 8 * 256;
    float* Px      = ws + off; off += 256 * 1024;
    float* Py      = ws + off; off += 256 * 1024;
    float* Qx      = ws + off; off += 256 * 512;
    float* Qy      = ws + off; off += 256 * 512;
    unsigned short* m1f_p = (unsigned short*)(ws + off); off += (size_t)8 * 512 * 512 / 2;
    unsigned short* m1g_p = (unsigned short*)(ws + off); off += (size_t)8 * 512 * 512 / 2;
    unsigned short* m2f_p = (unsigned short*)(ws + off); off += (size_t)8 * 256 * 256 / 2;
    unsigned short* m2g_p = (unsigned short*)(ws + off); off += (size_t)8 * 256 * 256 / 2;
    unsigned short* w2m_p = (unsigned short*)(ws + off); off += (size_t)512 * 1024 / 2;

    // ---- constants (3 dispatches) ----
    sgrid_kernel<<<32, 256, 0, stream>>>(sgrid);
    wn_all<<<12288, 256, 0, stream>>>(m1_vf, m1_gf, s1f, m1_vg, m1_gg, s1g,
                                      m2_vf, m2_gf, s2f, m2_vg, m2_gg, s2g);
    repack_all<<<2816, 256, 0, stream>>>(m1_vf, m1_vg, m2_vf, m2_vg, w2,
                                         m1f_p, m1g_p, m2f_p, m2g_p, w2m_p);

    // ---- conv trunk: one memset, 5x (partials + finalize) ----
    hipMemsetAsync(cbA, 0, convN * sizeof(float), stream);
    conv_part<<<dim3(768, 7), 256, 0, stream>>>(feature, cw1, cbA, 448, 192, 8, 1);
    conv_finalize<<<(768 * 64) / 256, 256, 0, stream>>>(cbA, cb1, 64, 768 * 64);
    conv_part<<<dim3(768, 4), 256, 0, stream>>>(cbA, cw2, cbB, 256, 256, 8, 1);
    conv_finalize<<<(768 * 64) / 256, 256, 0, stream>>>(cbB, cb2, 64, 768 * 64);
    conv_part<<<dim3(768, 6), 256, 0, stream>>>(cbB, cw3, cbC, 384, 384, 8, 1);
    conv_finalize<<<(768 * 64) / 256, 256, 0, stream>>>(cbC, cb3, 64, 768 * 64);
    conv_part<<<dim3(768, 4), 256, 0, stream>>>(cbC, cw4, cbD, 256, 256, 8, 0);     // ->6x6
    conv_finalize<<<(768 * 36 + 255) / 256, 256, 0, stream>>>(cbD, cb4, 36, 768 * 36);
    conv_part<<<dim3(128, 12), 256, 0, stream>>>(cbD, cw5, featbuf, 768, 128, 6, 0); // ->4x4
    conv_finalize<<<(2048 + 255) / 256, 256, 0, stream>>>(featbuf, cb5, 16, 2048);

    // ---- c1, P/Q tables ----
    feat_c1_kernel<<<1024 / 4, 256, 0, stream>>>(featbuf, w1, b1, c1);
    pq_kernel<<<(256 * 1024 + 256 * 512) / 256, 256, 0, stream>>>(sgrid, w1, c1, w2, Px, Py, Qx, Qy);

    // ---- fused per-position MLP: 1024 blocks x 64 rows ----
    size_t lds_bytes = (size_t)64 * RS * sizeof(unsigned short);   // 132096
    hipFuncSetAttribute(reinterpret_cast<const void*>(fused_mlp),
                        hipFuncAttributeMaxDynamicSharedMemorySize, (int)lds_bytes);
    fused_mlp<<<1024, 512, lds_bytes, stream>>>(
        Px, Py, Qx, Qy,
        m1f_p, s1f, m1_bf, m1g_p, s1g, m1_bg,
        w2m_p, b2,
        m2f_p, s2f, m2_bf, m2g_p, s2g, m2_bg,
        w3, b3, out);
}